// Round 1
// baseline (160.507 us; speedup 1.0000x reference)
//
#include <hip/hip_runtime.h>
#include <hip/hip_bf16.h>
#include <stdint.h>

// Problem constants: B=2, L=2048, D=1024, H=16, hd=64, scale=1/8.

typedef __bf16 bf16x8 __attribute__((ext_vector_type(8)));
typedef float f32x4 __attribute__((ext_vector_type(4)));

__device__ __forceinline__ unsigned short f2bf(float f) {
  union { float f; unsigned int u; } v; v.f = f;
  unsigned int r = v.u + 0x7FFFu + ((v.u >> 16) & 1u);  // RNE
  return (unsigned short)(r >> 16);
}
__device__ __forceinline__ float b2f(unsigned short u) {
  union { unsigned int u; float f; } v; v.u = ((unsigned int)u) << 16;
  return v.f;
}

__device__ __forceinline__ void gl2lds16(const void* gptr, void* lptr) {
  __builtin_amdgcn_global_load_lds(
      (const __attribute__((address_space(1))) unsigned int*)gptr,
      (__attribute__((address_space(3))) unsigned int*)lptr, 16, 0, 0);
}

// ---------------- fp32 -> bf16 conversion ----------------
__global__ void cvt_bf16(const float4* __restrict__ in, ushort4* __restrict__ out, int n4) {
  int i = blockIdx.x * 256 + threadIdx.x;
  if (i >= n4) return;
  float4 v = in[i];
  ushort4 o;
  o.x = f2bf(v.x); o.y = f2bf(v.y); o.z = f2bf(v.z); o.w = f2bf(v.w);
  out[i] = o;
}

// ---------------- GEMM: C[M,N] = A[M,K] * B[N,K]^T (both K-contiguous) ----------------
// m97-style: 128x128 tile, BK=32, 4 waves (2x2), global_load_lds width 16.
template<int OUT_BF16>
__global__ __launch_bounds__(256) void gemm_bt(
    const __hip_bfloat16* __restrict__ A,
    const __hip_bfloat16* __restrict__ B,
    void* __restrict__ C, int M, int N, int K) {
  __shared__ __align__(16) __hip_bfloat16 As[128 * 32];
  __shared__ __align__(16) __hip_bfloat16 Bs[128 * 32];
  const int tid = threadIdx.x;
  const int lane = tid & 63;
  const int wave = tid >> 6;
  const int wm = (wave >> 1) * 64, wn = (wave & 1) * 64;
  const int g = lane >> 4, lr = lane & 15;
  const int m0 = blockIdx.y * 128, n0 = blockIdx.x * 128;
  f32x4 acc[4][4] = {};

  const char* Ag = (const char*)(A + (size_t)m0 * K);
  const char* Bg = (const char*)(B + (size_t)n0 * K);
  const size_t ldb = (size_t)K * 2;  // row stride bytes

  for (int kt = 0; kt < K; kt += 32) {
    const char* Ak = Ag + (size_t)kt * 2;
    const char* Bk = Bg + (size_t)kt * 2;
#pragma unroll
    for (int j = 0; j < 2; ++j) {
      int c = tid + j * 256;           // 16B chunk index, 0..511
      int row = c >> 2;                // 4 chunks per 64B row
      int colb = (c & 3) * 16;
      gl2lds16(Ak + (size_t)row * ldb + colb, (char*)As + c * 16);
      gl2lds16(Bk + (size_t)row * ldb + colb, (char*)Bs + c * 16);
    }
    asm volatile("s_waitcnt vmcnt(0)" ::: "memory");
    __syncthreads();
    bf16x8 af[4], bfr[4];
#pragma unroll
    for (int i = 0; i < 4; ++i)
      af[i] = *(const bf16x8*)((const char*)As + (size_t)(wm + i * 16 + lr) * 64 + g * 16);
#pragma unroll
    for (int i = 0; i < 4; ++i)
      bfr[i] = *(const bf16x8*)((const char*)Bs + (size_t)(wn + i * 16 + lr) * 64 + g * 16);
#pragma unroll
    for (int i = 0; i < 4; ++i)
#pragma unroll
      for (int j = 0; j < 4; ++j)
        acc[i][j] = __builtin_amdgcn_mfma_f32_16x16x32_bf16(af[i], bfr[j], acc[i][j], 0, 0, 0);
    __syncthreads();
  }

  // Epilogue. C/D layout: n = lane&15 (+16*nf), m = 4*(lane>>4)+reg (+16*mf).
#pragma unroll
  for (int i = 0; i < 4; ++i) {
#pragma unroll
    for (int j = 0; j < 4; ++j) {
      int n = n0 + wn + j * 16 + lr;
#pragma unroll
      for (int r = 0; r < 4; ++r) {
        int m = m0 + wm + i * 16 + g * 4 + r;
        float v = acc[i][j][r];
        if (OUT_BF16) {
          ((unsigned short*)C)[(size_t)m * N + n] = f2bf(v);
        } else {
          ((float*)C)[(size_t)m * N + n] = v;
        }
      }
    }
  }
}

// ---------------- RoPE + scatter to per-head Q,K,V(transposed) ----------------
// qkv: bf16 [B*L][3*1024]. Writes:
//   Qs[bh][l][64] (scaled by 1/8), Ks[bh][l][64], Vt[bh][64][L].
__global__ void rope_scatter(const __hip_bfloat16* __restrict__ qkv,
                             __hip_bfloat16* __restrict__ Qs,
                             __hip_bfloat16* __restrict__ Ks,
                             __hip_bfloat16* __restrict__ Vt) {
  const int t = blockIdx.x * 256 + threadIdx.x;  // 262144 total
  const int i = t & 31;          // rope pair index 0..31
  const int lc = (t >> 5) & 255; // chunk of 8 positions
  const int h = (t >> 13) & 15;
  const int b = t >> 17;
  const float inv_freq = powf(10000.0f, -(float)i * (1.0f / 32.0f));
  const unsigned short* qk = (const unsigned short*)qkv;
  unsigned short v0[8], v1[8];
#pragma unroll
  for (int j = 0; j < 8; ++j) {
    const int l = lc * 8 + j;
    const size_t row = ((size_t)(b * 2048 + l)) * 3072;
    float s, c;
    sincosf((float)l * inv_freq, &s, &c);
    ushort2 qp = *(const ushort2*)(qk + row + h * 64 + 2 * i);
    ushort2 kp = *(const ushort2*)(qk + row + 1024 + h * 64 + 2 * i);
    ushort2 vp = *(const ushort2*)(qk + row + 2048 + h * 64 + 2 * i);
    float x1 = b2f(qp.x), x2 = b2f(qp.y);
    float y1 = b2f(kp.x), y2 = b2f(kp.y);
    size_t oidx = (((size_t)(b * 16 + h)) * 2048 + l) * 64 + 2 * i;
    ushort2 qo, ko;
    qo.x = f2bf((x1 * c - x2 * s) * 0.125f);
    qo.y = f2bf((x1 * s + x2 * c) * 0.125f);
    ko.x = f2bf(y1 * c - y2 * s);
    ko.y = f2bf(y1 * s + y2 * c);
    *(ushort2*)((unsigned short*)Qs + oidx) = qo;
    *(ushort2*)((unsigned short*)Ks + oidx) = ko;
    v0[j] = vp.x; v1[j] = vp.y;
  }
  unsigned short* Vtu = (unsigned short*)Vt;
  const size_t vrow0 = (((size_t)(b * 16 + h)) * 64 + 2 * i) * 2048 + lc * 8;
  const size_t vrow1 = vrow0 + 2048;
  *(ushort4*)(Vtu + vrow0)     = make_ushort4(v0[0], v0[1], v0[2], v0[3]);
  *(ushort4*)(Vtu + vrow0 + 4) = make_ushort4(v0[4], v0[5], v0[6], v0[7]);
  *(ushort4*)(Vtu + vrow1)     = make_ushort4(v1[0], v1[1], v1[2], v1[3]);
  *(ushort4*)(Vtu + vrow1 + 4) = make_ushort4(v1[4], v1[5], v1[6], v1[7]);
}

// ---------------- Flash attention ----------------
// Grid: 1024 blocks = (bh 0..31) x (qtile 0..31). 4 waves, 16 q-rows each.
// Swapped QK^T: S^T = mfma(A=K, B=Q) so each lane owns P values of one q-row.
// K/Vt LDS tiles XOR-swizzled (source-side pre-swizzle + read-side swizzle).
__global__ __launch_bounds__(256) void attn_fwd(
    const __hip_bfloat16* __restrict__ Qs,
    const __hip_bfloat16* __restrict__ Ks,
    const __hip_bfloat16* __restrict__ Vt,
    __hip_bfloat16* __restrict__ Ob) {
  constexpr int L = 2048;
  __shared__ __align__(16) __hip_bfloat16 Kt[64 * 64];
  __shared__ __align__(16) __hip_bfloat16 Vts[64 * 64];
  __shared__ __align__(16) __hip_bfloat16 Pw[4][16][72];  // padded rows (144B)
  const int tid = threadIdx.x, lane = tid & 63, w = tid >> 6;
  const int g = lane >> 4, lr = lane & 15;
  const int bh = blockIdx.x >> 5;
  const int qt = blockIdx.x & 31;
  const int q = qt * 64 + w * 16 + lr;

  const __hip_bfloat16* Qrow = Qs + ((size_t)bh * L + q) * 64;
  bf16x8 qf[2];
  qf[0] = *(const bf16x8*)(Qrow + g * 8);
  qf[1] = *(const bf16x8*)(Qrow + 32 + g * 8);

  f32x4 oacc[4] = {};
  float mrun = -1e30f, lpart = 0.0f;
  const char* Kbase = (const char*)(Ks + (size_t)bh * L * 64);
  const char* Vbase = (const char*)(Vt + (size_t)bh * 64 * L);

  for (int kt = 0; kt < L / 64; ++kt) {
    // Stage K tile (contiguous 8KB) and Vt tile (64 rows x 128B, stride L*2B),
    // with source-side pre-swizzle so swizzled reads see linear tile bytes.
#pragma unroll
    for (int j = 0; j < 2; ++j) {
      int c = tid + j * 256;
      int o = c * 16;
      int os = o ^ (((o >> 7) & 7) << 4);  // involution
      gl2lds16(Kbase + (size_t)kt * 8192 + os, (char*)Kt + o);
      int vrow = os >> 7, vcol = os & 127;
      gl2lds16(Vbase + (size_t)vrow * (L * 2) + kt * 128 + vcol, (char*)Vts + o);
    }
    asm volatile("s_waitcnt vmcnt(0)" ::: "memory");
    __syncthreads();

    // QK^T (swapped): sacc[mf] holds S^T[k-rows mf*16+4g+r][q=lr]
    f32x4 sacc[4] = {};
#pragma unroll
    for (int mf = 0; mf < 4; ++mf) {
      int row = mf * 16 + lr;
#pragma unroll
      for (int ds = 0; ds < 2; ++ds) {
        int addr = (row * 128 + ds * 64 + g * 16) ^ ((row & 7) << 4);
        bf16x8 a = *(const bf16x8*)((const char*)Kt + addr);
        sacc[mf] = __builtin_amdgcn_mfma_f32_16x16x32_bf16(a, qf[ds], sacc[mf], 0, 0, 0);
      }
    }

    // Online softmax (per lane: 16 scores of its q-row; row spans 4 lane-groups)
    float tmax = -1e30f;
#pragma unroll
    for (int mf = 0; mf < 4; ++mf)
#pragma unroll
      for (int r = 0; r < 4; ++r) tmax = fmaxf(tmax, sacc[mf][r]);
    tmax = fmaxf(tmax, __shfl_xor(tmax, 16));
    tmax = fmaxf(tmax, __shfl_xor(tmax, 32));
    float mnew = fmaxf(mrun, tmax);
    float alpha = __expf(mrun - mnew);
    mrun = mnew;
    lpart *= alpha;
#pragma unroll
    for (int d = 0; d < 4; ++d) oacc[d] = oacc[d] * alpha;
#pragma unroll
    for (int mf = 0; mf < 4; ++mf) {
      float p0 = __expf(sacc[mf][0] - mnew);
      float p1 = __expf(sacc[mf][1] - mnew);
      float p2 = __expf(sacc[mf][2] - mnew);
      float p3 = __expf(sacc[mf][3] - mnew);
      lpart += (p0 + p1) + (p2 + p3);
      ushort4 pk;
      pk.x = f2bf(p0); pk.y = f2bf(p1); pk.z = f2bf(p2); pk.w = f2bf(p3);
      *(ushort4*)((char*)(&Pw[w][lr][0]) + mf * 32 + g * 8) = pk;
    }
    asm volatile("s_waitcnt lgkmcnt(0)" ::: "memory");
    __builtin_amdgcn_sched_barrier(0);

    // PV: O^T = mfma(A=Vt, B=P); oacc[df] holds O^T[d=df*16+4g+r][q=lr]
#pragma unroll
    for (int ks = 0; ks < 2; ++ks) {
      bf16x8 pfrag = *(const bf16x8*)((const char*)(&Pw[w][lr][0]) + ks * 64 + g * 16);
#pragma unroll
      for (int df = 0; df < 4; ++df) {
        int row = df * 16 + lr;
        int addr = (row * 128 + ks * 64 + g * 16) ^ ((row & 7) << 4);
        bf16x8 a = *(const bf16x8*)((const char*)Vts + addr);
        oacc[df] = __builtin_amdgcn_mfma_f32_16x16x32_bf16(a, pfrag, oacc[df], 0, 0, 0);
      }
    }
    __syncthreads();
  }

  float lsum = lpart;
  lsum += __shfl_xor(lsum, 16);
  lsum += __shfl_xor(lsum, 32);
  float inv = 1.0f / lsum;

  const int b = bh >> 4, h = bh & 15;
  unsigned short* orow = (unsigned short*)Ob + ((size_t)(b * L + q)) * 1024 + h * 64;
#pragma unroll
  for (int df = 0; df < 4; ++df) {
    ushort4 o4;
    o4.x = f2bf(oacc[df][0] * inv);
    o4.y = f2bf(oacc[df][1] * inv);
    o4.z = f2bf(oacc[df][2] * inv);
    o4.w = f2bf(oacc[df][3] * inv);
    *(ushort4*)(orow + df * 16 + g * 4) = o4;
  }
}

// ---------------- launch ----------------
extern "C" void kernel_launch(void* const* d_in, const int* in_sizes, int n_in,
                              void* d_out, int out_size, void* d_ws, size_t ws_size,
                              hipStream_t stream) {
  (void)in_sizes; (void)n_in; (void)out_size; (void)ws_size;
  const float* x    = (const float*)d_in[0];   // [2,2048,1024]
  const float* wqkv = (const float*)d_in[1];   // [3072,1024]
  const float* wout = (const float*)d_in[2];   // [1024,1024]

  char* ws = (char*)d_ws;
  // Workspace layout (needs 64 MB):
  auto* xb   = (__hip_bfloat16*)(ws + (size_t)(0u));          // 8 MB
  auto* wqb  = (__hip_bfloat16*)(ws + ((size_t)8u << 20));    // 6 MB
  auto* wob  = (__hip_bfloat16*)(ws + ((size_t)14u << 20));   // 2 MB
  auto* qkvb = (__hip_bfloat16*)(ws + ((size_t)16u << 20));   // 24 MB [4096][3072]
  auto* Ob   = (__hip_bfloat16*)(ws + ((size_t)16u << 20));   // 8 MB, overlaps dead qkvb
  auto* Qsb  = (__hip_bfloat16*)(ws + ((size_t)40u << 20));   // 8 MB [32][2048][64]
  auto* Ksb  = (__hip_bfloat16*)(ws + ((size_t)48u << 20));   // 8 MB
  auto* Vtb  = (__hip_bfloat16*)(ws + ((size_t)56u << 20));   // 8 MB [32][64][2048]

  cvt_bf16<<<4096, 256, 0, stream>>>((const float4*)x,    (ushort4*)xb,  1048576);
  cvt_bf16<<<3072, 256, 0, stream>>>((const float4*)wqkv, (ushort4*)wqb, 786432);
  cvt_bf16<<<1024, 256, 0, stream>>>((const float4*)wout, (ushort4*)wob, 262144);

  gemm_bt<1><<<dim3(24, 32), 256, 0, stream>>>(xb, wqb, (void*)qkvb, 4096, 3072, 1024);
  rope_scatter<<<1024, 256, 0, stream>>>(qkvb, Qsb, Ksb, Vtb);
  attn_fwd<<<1024, 256, 0, stream>>>(Qsb, Ksb, Vtb, Ob);
  gemm_bt<0><<<dim3(8, 32), 256, 0, stream>>>(Ob, wob, d_out, 4096, 1024, 1024);
}